// Round 13
// baseline (1560.881 us; speedup 1.0000x reference)
//
#include <hip/hip_runtime.h>
#include <hip/hip_bf16.h>
#include <math.h>

// Problem constants
#define BATCH   16
#define NTOK    393            // 3*128 + 9
#define ROWS    (BATCH * NTOK) // 6288
#define MPAD    6400           // 50 * 128
#define DMODEL  512
#define NHEAD   8
#define DHEAD   64
#define FCDIM   2048
#define DEPTH   4
#define NPRED   20
#define ATTN_PER_LAYER ((size_t)BATCH * NHEAD * NTOK * NTOK) // 19,769,472

typedef _Float16 half_t;
typedef __attribute__((ext_vector_type(8))) _Float16 half8;
typedef __attribute__((ext_vector_type(4))) _Float16 half4;
typedef __attribute__((ext_vector_type(2))) _Float16 half2v;
typedef __attribute__((ext_vector_type(4))) float f32x4;

typedef __attribute__((address_space(1))) const void gas_void;
typedef __attribute__((address_space(3))) void las_void;

// ---------------------------------------------------------------------------
// Embedding: per-agent linear projections + sinusoidal PE + spec tokens (fp32 x)
// ---------------------------------------------------------------------------
__global__ __launch_bounds__(256) void embed_kernel(
    const float* __restrict__ x_in, const float* __restrict__ spec,
    const float* __restrict__ Wc, const float* __restrict__ bc,
    const float* __restrict__ Wb, const float* __restrict__ bb,
    const float* __restrict__ Wt, const float* __restrict__ btg,
    const float* __restrict__ specW, const float* __restrict__ specB,
    float* __restrict__ X) {
  int bt = blockIdx.x;
  int b = bt / NTOK, t = bt % NTOK;
  int tid = threadIdx.x;
  for (int d = tid; d < DMODEL; d += 256) {
    float val;
    if (t < 384) {
      int a = t >> 7, p = t & 127;
      const float* W; const float* bias; int nf, f0;
      if (a == 0)      { W = Wc; bias = bc;  nf = 9;  f0 = 0;  }
      else if (a == 1) { W = Wb; bias = bb;  nf = 12; f0 = 9;  }
      else             { W = Wt; bias = btg; nf = 8;  f0 = 21; }
      val = bias[d];
      const float* xi = x_in + ((size_t)b * 128 + p) * 29 + f0;
      for (int f = 0; f < nf; ++f) val += xi[f] * W[f * DMODEL + d];
      float iv = (float)((d >> 1) << 1);
      float div = expf(-logf(10000.0f) * iv / (float)DMODEL);
      float aa = (float)a * div, tt = (float)p * div;
      val += (d & 1) ? (cosf(aa) + cosf(tt)) : (sinf(aa) + sinf(tt));
    } else {
      int f = t - 384;
      val = spec[b * 9 + f] * specW[f * DMODEL + d] + specB[f * DMODEL + d];
    }
    X[((size_t)b * NTOK + t) * DMODEL + d] = val;
  }
}

// ---------------------------------------------------------------------------
// LayerNorm fp32 -> f16. Grid MPAD rows; rows >= ROWS write zeros (padding).
// ---------------------------------------------------------------------------
__global__ __launch_bounds__(256) void ln_kernel(
    const float* __restrict__ X, const float* __restrict__ g,
    const float* __restrict__ b, half_t* __restrict__ Y) {
  int row = blockIdx.x;
  int tid = threadIdx.x;
  if (row >= ROWS) {
    half2v z = {(half_t)0.f, (half_t)0.f};
    *(half2v*)(Y + (size_t)row * DMODEL + tid * 2) = z;
    return;
  }
  const float* xr = X + (size_t)row * DMODEL;
  float2 v = *(const float2*)(xr + tid * 2);
  float s = v.x + v.y;
  for (int off = 32; off; off >>= 1) s += __shfl_down(s, off);
  __shared__ float red[4];
  if ((tid & 63) == 0) red[tid >> 6] = s;
  __syncthreads();
  float mu = (red[0] + red[1] + red[2] + red[3]) * (1.0f / DMODEL);
  __syncthreads();
  float dx = v.x - mu, dy = v.y - mu;
  float s2 = dx * dx + dy * dy;
  for (int off = 32; off; off >>= 1) s2 += __shfl_down(s2, off);
  if ((tid & 63) == 0) red[tid >> 6] = s2;
  __syncthreads();
  float var = (red[0] + red[1] + red[2] + red[3]) * (1.0f / DMODEL);
  float rs = rsqrtf(var + 1e-5f);
  half2v o;
  o[0] = (half_t)(dx * rs * g[tid * 2]     + b[tid * 2]);
  o[1] = (half_t)(dy * rs * g[tid * 2 + 1] + b[tid * 2 + 1]);
  *(half2v*)(Y + (size_t)row * DMODEL + tid * 2) = o;
}

// ---------------------------------------------------------------------------
// Weight convert+transpose: W[K][N] fp32 -> Wt[N][K] f16. 32x32 tiles.
// ---------------------------------------------------------------------------
__global__ __launch_bounds__(256) void wconv_kernel(
    const float* __restrict__ W, half_t* __restrict__ Wt, int K, int N) {
  __shared__ float T[32][33];
  int n0 = blockIdx.x * 32, k0 = blockIdx.y * 32;
  int tx = threadIdx.x & 31, ty = threadIdx.x >> 5; // ty 0..7
  #pragma unroll
  for (int r = 0; r < 4; ++r)
    T[ty + r * 8][tx] = W[(size_t)(k0 + ty + r * 8) * N + n0 + tx];
  __syncthreads();
  #pragma unroll
  for (int r = 0; r < 4; ++r)
    Wt[(size_t)(n0 + ty + r * 8) * K + k0 + tx] = (half_t)T[tx][ty + r * 8];
}

// ---------------------------------------------------------------------------
// MFMA GEMM: C = epilogue(A[Mpad][K] @ Wt[N][K]^T). f16 in, fp32 accum.
// 128x128 tile, BK=32, 4 waves (2x2), 4x4 16x16 fragments per wave.
// Staging via global_load_lds width=16 (direct HBM->LDS, no VGPR roundtrip):
// wave w, lane i -> LDS row (w*16 + i/4) [+64 for 2nd issue], 16B chunk i%4.
// LDS dest = wave-uniform base + lane*16 (HW requirement); linear row-major
// [128][32] f16 layout matches exactly.
// ---------------------------------------------------------------------------
template <bool BIAS, bool RES, bool GELU_ACT, bool OUT_F16>
__global__ __launch_bounds__(256) void mfma_gemm(
    const half_t* __restrict__ A, const half_t* __restrict__ Wt,
    const float* __restrict__ bias, const float* __restrict__ R,
    void* __restrict__ Cout, int Mreal, int K, int N) {
  __shared__ __align__(16) half_t As[128 * 32];
  __shared__ __align__(16) half_t Bs[128 * 32];
  int tid = threadIdx.x;
  int lane = tid & 63, wid = tid >> 6;
  int brow = blockIdx.y * 128;
  int bcol = blockIdx.x * 128;
  int wr = wid >> 1, wc = wid & 1;
  int l15 = lane & 15, l4 = lane >> 4;

  f32x4 acc[4][4];
  #pragma unroll
  for (int i = 0; i < 4; ++i)
    #pragma unroll
    for (int n = 0; n < 4; ++n)
      #pragma unroll
      for (int r = 0; r < 4; ++r) acc[i][n][r] = 0.0f;

  // global_load_lds staging addresses: wave-uniform LDS base, per-lane global.
  int srow = wid * 16 + (lane >> 2); // row within 16-row group
  int skseg = (lane & 3) * 8;        // 16B chunk
  const half_t* AgW = A  + (size_t)(brow + srow) * K + skseg;
  const half_t* BgW = Wt + (size_t)(bcol + srow) * K + skseg;
  half_t* AsB0 = &As[(wid * 16) * 32];
  half_t* AsB1 = &As[(64 + wid * 16) * 32];
  half_t* BsB0 = &Bs[(wid * 16) * 32];
  half_t* BsB1 = &Bs[(64 + wid * 16) * 32];

  for (int k0 = 0; k0 < K; k0 += 32) {
    __syncthreads();
    __builtin_amdgcn_global_load_lds((gas_void*)(AgW + k0),                 (las_void*)AsB0, 16, 0, 0);
    __builtin_amdgcn_global_load_lds((gas_void*)(AgW + (size_t)64 * K + k0), (las_void*)AsB1, 16, 0, 0);
    __builtin_amdgcn_global_load_lds((gas_void*)(BgW + k0),                 (las_void*)BsB0, 16, 0, 0);
    __builtin_amdgcn_global_load_lds((gas_void*)(BgW + (size_t)64 * K + k0), (las_void*)BsB1, 16, 0, 0);
    __syncthreads();
    half8 af[4], bf[4];
    #pragma unroll
    for (int i = 0; i < 4; ++i)
      af[i] = *(const half8*)&As[(wr * 64 + i * 16 + l15) * 32 + l4 * 8];
    #pragma unroll
    for (int n = 0; n < 4; ++n)
      bf[n] = *(const half8*)&Bs[(wc * 64 + n * 16 + l15) * 32 + l4 * 8];
    #pragma unroll
    for (int i = 0; i < 4; ++i)
      #pragma unroll
      for (int n = 0; n < 4; ++n)
        acc[i][n] = __builtin_amdgcn_mfma_f32_16x16x32_f16(af[i], bf[n], acc[i][n], 0, 0, 0);
  }

  // Epilogue. C/D layout: col = lane&15, row = (lane>>4)*4 + reg [m89-verified]
  #pragma unroll
  for (int i = 0; i < 4; ++i) {
    #pragma unroll
    for (int n = 0; n < 4; ++n) {
      int gcol = bcol + wc * 64 + n * 16 + l15;
      #pragma unroll
      for (int r = 0; r < 4; ++r) {
        int grow = brow + wr * 64 + i * 16 + l4 * 4 + r;
        float v = acc[i][n][r];
        if (BIAS) v += bias[gcol];
        if (GELU_ACT) v = 0.5f * v * (1.0f + erff(v * 0.70710678118f));
        if (OUT_F16) {
          ((half_t*)Cout)[(size_t)grow * N + gcol] = (half_t)v;
        } else {
          if (grow < Mreal) {
            if (RES) v += R[(size_t)grow * N + gcol];
            ((float*)Cout)[(size_t)grow * N + gcol] = v;
          }
        }
      }
    }
  }
}

// ---------------------------------------------------------------------------
// V transpose: qkv V-region [b,j,h,d] f16 -> Vt[bh][64][400] f16, zero-padded
// cols >= 393. One block per bh.
// ---------------------------------------------------------------------------
__global__ __launch_bounds__(256) void vtrans_kernel(
    const half_t* __restrict__ qkv, half_t* __restrict__ Vt) {
  int bh = blockIdx.x;
  int b = bh >> 3, hd = bh & 7;
  __shared__ half_t Vl[64][72]; // 144B rows (16B aligned)
  int tid = threadIdx.x;
  for (int j0 = 0; j0 < 400; j0 += 64) {
    int jj = tid >> 2, d8 = (tid & 3) * 16;
    int gj = j0 + jj;
    if (gj < NTOK) {
      const int4* src = (const int4*)(qkv + ((size_t)(b * NTOK + gj)) * 1536 + 1024 + hd * 64 + d8);
      *(int4*)&Vl[jj][d8]     = src[0];
      *(int4*)&Vl[jj][d8 + 8] = src[1];
    } else {
      half8 z;
      #pragma unroll
      for (int t = 0; t < 8; ++t) z[t] = (half_t)0.f;
      *(half8*)&Vl[jj][d8]     = z;
      *(half8*)&Vl[jj][d8 + 8] = z;
    }
    __syncthreads();
    int d = tid >> 2, j8 = (tid & 3) * 16;
    int cj = j0 + j8;
    if (cj < 400) {
      half_t tmp[16];
      #pragma unroll
      for (int k = 0; k < 16; ++k) tmp[k] = Vl[j8 + k][d];
      half_t* dst = Vt + ((size_t)bh * 64 + d) * 400 + cj;
      *(int4*)dst       = *(int4*)&tmp[0];
      *(int4*)(dst + 8) = *(int4*)&tmp[8];
    }
    __syncthreads();
  }
}

// ---------------------------------------------------------------------------
// Fused attention: per (32-row i-tile, bh). MFMA scores with per-16x16-tile
// mask select (block boundaries are 16-aligned), softmax in LDS, fp32 attn
// write to d_out, MFMA PV from Vt. 4 waves: wave w -> rows (w>>1)*16,
// j/d parity (w&1).
// ---------------------------------------------------------------------------
__global__ __launch_bounds__(256) void fused_attn_kernel(
    const half_t* __restrict__ qkv, const half_t* __restrict__ qks,
    const half_t* __restrict__ Vt, float* __restrict__ Sout,
    half_t* __restrict__ O) {
  int bh = blockIdx.y;
  int b = bh >> 3, hd = bh & 7;
  int i0 = blockIdx.x * 32;
  __shared__ float S[32][400];
  __shared__ float inv[32];
  int tid = threadIdx.x, lane = tid & 63, wid = tid >> 6;
  int r = wid >> 1, cpar = wid & 1;
  int l15 = lane & 15, l4 = lane >> 4;

  // Per-wave Q/Qs A-fragments (16 rows) loaded straight from global.
  int qrow = i0 + r * 16 + l15;
  half8 qf[2], qsf[2];
  if (qrow < NTOK) {
    const half_t* qp  = qkv + ((size_t)(b * NTOK + qrow)) * 1536 + hd * 64 + l4 * 8;
    const half_t* qsp = qks + ((size_t)(b * NTOK + qrow)) * 1024 + hd * 64 + l4 * 8;
    qf[0]  = *(const half8*)qp;        qf[1]  = *(const half8*)(qp + 32);
    qsf[0] = *(const half8*)qsp;       qsf[1] = *(const half8*)(qsp + 32);
  } else {
    #pragma unroll
    for (int t = 0; t < 8; ++t) {
      qf[0][t] = (half_t)0.f; qf[1][t] = (half_t)0.f;
      qsf[0][t] = (half_t)0.f; qsf[1][t] = (half_t)0.f;
    }
  }
  const float scale = 0.125f; // 64^-0.5
  int i0t = i0 + r * 16;

  // Scores: this wave handles j-tiles of its parity.
  for (int jt = cpar; jt < 25; jt += 2) {
    int j0 = jt * 16;
    bool use_s = (i0t < 384) && (j0 < 384) && ((i0t >> 7) == (j0 >> 7));
    int krow = j0 + l15;
    half8 kf0, kf1;
    if (krow < NTOK) {
      const half_t* kp = use_s
          ? (qks + ((size_t)(b * NTOK + krow)) * 1024 + 512 + hd * 64 + l4 * 8)
          : (qkv + ((size_t)(b * NTOK + krow)) * 1536 + 512 + hd * 64 + l4 * 8);
      kf0 = *(const half8*)kp;
      kf1 = *(const half8*)(kp + 32);
    } else {
      #pragma unroll
      for (int t = 0; t < 8; ++t) { kf0[t] = (half_t)0.f; kf1[t] = (half_t)0.f; }
    }
    f32x4 acc = {0.f, 0.f, 0.f, 0.f};
    acc = __builtin_amdgcn_mfma_f32_16x16x32_f16(use_s ? qsf[0] : qf[0], kf0, acc, 0, 0, 0);
    acc = __builtin_amdgcn_mfma_f32_16x16x32_f16(use_s ? qsf[1] : qf[1], kf1, acc, 0, 0, 0);
    #pragma unroll
    for (int t = 0; t < 4; ++t)
      S[r * 16 + l4 * 4 + t][j0 + l15] = acc[t] * scale;
  }
  __syncthreads();

  // Softmax: 8 threads per row.
  {
    int row = tid >> 3, sub = tid & 7;
    float mx = -1e30f;
    for (int c = sub; c < NTOK; c += 8) mx = fmaxf(mx, S[row][c]);
    mx = fmaxf(mx, __shfl_xor(mx, 1));
    mx = fmaxf(mx, __shfl_xor(mx, 2));
    mx = fmaxf(mx, __shfl_xor(mx, 4));
    float sum = 0.0f;
    for (int c = sub; c < NTOK; c += 8) {
      float e = __expf(S[row][c] - mx);
      S[row][c] = e;
      sum += e;
    }
    sum += __shfl_xor(sum, 1);
    sum += __shfl_xor(sum, 2);
    sum += __shfl_xor(sum, 4);
    if (sub == 0) inv[row] = 1.0f / sum;
  }
  __syncthreads();

  // Write normalized attn to d_out (fp32), coalesced per row.
  for (int rr = 0; rr < 32; ++rr) {
    int gi = i0 + rr;
    if (gi >= NTOK) break;
    float iv = inv[rr];
    float* dst = Sout + ((size_t)bh * NTOK + gi) * NTOK;
    for (int c = tid; c < NTOK; c += 256) dst[c] = S[rr][c] * iv;
  }

  // PV via MFMA: wave computes rows r*16..+16, d-tiles cpar*32 + {0,16}.
  f32x4 oacc[2];
  #pragma unroll
  for (int dt = 0; dt < 2; ++dt)
    #pragma unroll
    for (int t = 0; t < 4; ++t) oacc[dt][t] = 0.0f;
  int arow = r * 16 + l15;
  float aiv = inv[arow];
  for (int kc = 0; kc < 13; ++kc) {
    int k0 = kc * 32;
    bool lvalid = (k0 + l4 * 8) < 400; // last chunk: lanes with k>=400 zeroed
    half8 pa;
    if (lvalid) {
      #pragma unroll
      for (int t = 0; t < 8; ++t)
        pa[t] = (half_t)(S[arow][k0 + l4 * 8 + t] * aiv);
    } else {
      #pragma unroll
      for (int t = 0; t < 8; ++t) pa[t] = (half_t)0.f;
    }
    #pragma unroll
    for (int dt = 0; dt < 2; ++dt) {
      int d0 = cpar * 32 + dt * 16;
      half8 vb;
      if (lvalid) {
        vb = *(const half8*)(Vt + ((size_t)bh * 64 + d0 + l15) * 400 + k0 + l4 * 8);
      } else {
        #pragma unroll
        for (int t = 0; t < 8; ++t) vb[t] = (half_t)0.f;
      }
      oacc[dt] = __builtin_amdgcn_mfma_f32_16x16x32_f16(pa, vb, oacc[dt], 0, 0, 0);
    }
  }
  #pragma unroll
  for (int dt = 0; dt < 2; ++dt) {
    int d0 = cpar * 32 + dt * 16;
    #pragma unroll
    for (int t = 0; t < 4; ++t) {
      int i = i0 + r * 16 + l4 * 4 + t;
      if (i < NTOK)
        O[((size_t)(b * NTOK + i)) * DMODEL + hd * 64 + d0 + l15] = (half_t)oacc[dt][t];
    }
  }
}

// ---------------------------------------------------------------------------
// Final: mean-pool over tokens, LN, gen head. One block (512 thr) per batch.
// ---------------------------------------------------------------------------
__global__ __launch_bounds__(512) void final_kernel(
    const float* __restrict__ X, const float* __restrict__ gg,
    const float* __restrict__ gb, const float* __restrict__ gW,
    const float* __restrict__ gbias, float* __restrict__ out) {
  int b = blockIdx.x;
  int tid = threadIdx.x;
  const float* xb = X + (size_t)b * NTOK * DMODEL;
  float s = 0.0f;
  for (int t = 0; t < NTOK; ++t) s += xb[(size_t)t * DMODEL + tid];
  float pooled = s / (float)NTOK;
  __shared__ float red[8];
  float ss = pooled;
  for (int off = 32; off; off >>= 1) ss += __shfl_down(ss, off);
  if ((tid & 63) == 0) red[tid >> 6] = ss;
  __syncthreads();
  float mu = 0.0f;
  #pragma unroll
  for (int w = 0; w < 8; ++w) mu += red[w];
  mu *= (1.0f / DMODEL);
  __syncthreads();
  float dv = pooled - mu;
  float s2 = dv * dv;
  for (int off = 32; off; off >>= 1) s2 += __shfl_down(s2, off);
  if ((tid & 63) == 0) red[tid >> 6] = s2;
  __syncthreads();
  float var = 0.0f;
  #pragma unroll
  for (int w = 0; w < 8; ++w) var += red[w];
  var *= (1.0f / DMODEL);
  float y = dv * rsqrtf(var + 1e-5f) * gg[tid] + gb[tid];
  __shared__ float yl[DMODEL];
  yl[tid] = y;
  __syncthreads();
  if (tid < NPRED) {
    float acc = gbias[tid];
    for (int d = 0; d < DMODEL; ++d) acc += yl[d] * gW[d * NPRED + tid];
    out[b * NPRED + tid] = acc;
  }
}

// ---------------------------------------------------------------------------
extern "C" void kernel_launch(void* const* d_in, const int* in_sizes, int n_in,
                              void* d_out, int out_size, void* d_ws, size_t ws_size,
                              hipStream_t stream) {
  const float* x_in   = (const float*)d_in[0];
  const float* spec   = (const float*)d_in[1];
  const float* Wc     = (const float*)d_in[2];
  const float* bc     = (const float*)d_in[3];
  const float* Wb     = (const float*)d_in[4];
  const float* bb     = (const float*)d_in[5];
  const float* Wt     = (const float*)d_in[6];
  const float* bt     = (const float*)d_in[7];
  const float* spec_W = (const float*)d_in[8];
  const float* spec_b = (const float*)d_in[9];
  const float* ln1_g  = (const float*)d_in[10];
  const float* ln1_b  = (const float*)d_in[11];
  const float* qkv_W  = (const float*)d_in[12];
  const float* qks_W  = (const float*)d_in[13];
  const float* out_W  = (const float*)d_in[14];
  const float* out_b  = (const float*)d_in[15];
  const float* ln2_g  = (const float*)d_in[16];
  const float* ln2_b  = (const float*)d_in[17];
  const float* ff_W1  = (const float*)d_in[18];
  const float* ff_b1  = (const float*)d_in[19];
  const float* ff_W2  = (const float*)d_in[20];
  const float* ff_b2  = (const float*)d_in[21];
  const float* gen_g  = (const float*)d_in[22];
  const float* gen_bl = (const float*)d_in[23];
  const float* gen_W  = (const float*)d_in[24];
  const float* gen_b  = (const float*)d_in[25];

  // workspace carve (bytes)
  char* w = (char*)d_ws;
  float* x      = (float*)w;                    w += (size_t)ROWS * DMODEL * 4;
  half_t* h     = (half_t*)w;                   w += (size_t)MPAD * DMODEL * 2;   // also aliased as Vt
  half_t* qkv   = (half_t*)w;                   w += (size_t)MPAD * 1536 * 2;
  half_t* qks   = (half_t*)w;                   w += (size_t)MPAD * 1024 * 2;
  half_t* o     = (half_t*)w;                   w += (size_t)MPAD * DMODEL * 2;
  half_t* wt_qkv = (half_t*)w;                  w += (size_t)DEPTH * 1536 * 512 * 2;
  half_t* wt_qks = (half_t*)w;                  w += (size_t)DEPTH * 1024 * 512 * 2;
  half_t* wt_out = (half_t*)w;                  w += (size_t)DEPTH * 512 * 512 * 2;
  half_t* wt_ff1 = (half_t*)w;                  w += (size_t)DEPTH * 2048 * 512 * 2;
  half_t* wt_ff2 = (half_t*)w;                  w += (size_t)DEPTH * 512 * 2048 * 2;
  half_t* ff1   = qkv;   // alias: ff1 [MPAD][2048] fits in qkv+qks region
  half_t* Vt    = h;     // alias: Vt [128][64][400] f16 == h size exactly; h dead
                         // between qks-GEMM and ln2.

  float* out_f = (float*)d_out;

  // weight convert+transpose (every launch; same work each call)
  for (int l = 0; l < DEPTH; ++l) {
    wconv_kernel<<<dim3(1536 / 32, 512 / 32), 256, 0, stream>>>(
        qkv_W + (size_t)l * 512 * 1536, wt_qkv + (size_t)l * 1536 * 512, 512, 1536);
    wconv_kernel<<<dim3(1024 / 32, 512 / 32), 256, 0, stream>>>(
        qks_W + (size_t)l * 512 * 1024, wt_qks + (size_t)l * 1024 * 512, 512, 1024);
    wconv_kernel<<<dim3(512 / 32, 512 / 32), 256, 0, stream>>>(
        out_W + (size_t)l * 512 * 512, wt_out + (size_t)l * 512 * 512, 512, 512);
    wconv_kernel<<<dim3(2048 / 32, 512 / 32), 256, 0, stream>>>(
        ff_W1 + (size_t)l * 512 * 2048, wt_ff1 + (size_t)l * 2048 * 512, 512, 2048);
    wconv_kernel<<<dim3(512 / 32, 2048 / 32), 256, 0, stream>>>(
        ff_W2 + (size_t)l * 2048 * 512, wt_ff2 + (size_t)l * 512 * 2048, 2048, 512);
  }

  embed_kernel<<<BATCH * NTOK, 256, 0, stream>>>(
      x_in, spec, Wc, bc, Wb, bb, Wt, bt, spec_W, spec_b, x);

  for (int l = 0; l < DEPTH; ++l) {
    float* attn = out_f + 320 + (size_t)l * ATTN_PER_LAYER;

    ln_kernel<<<MPAD, 256, 0, stream>>>(x, ln1_g + l * DMODEL, ln1_b + l * DMODEL, h);

    mfma_gemm<false, false, false, true><<<dim3(1536 / 128, MPAD / 128), 256, 0, stream>>>(
        h, wt_qkv + (size_t)l * 1536 * 512, nullptr, nullptr, qkv, ROWS, 512, 1536);
    mfma_gemm<false, false, false, true><<<dim3(1024 / 128, MPAD / 128), 256, 0, stream>>>(
        h, wt_qks + (size_t)l * 1024 * 512, nullptr, nullptr, qks, ROWS, 512, 1024);

    // h is dead now: reuse as Vt
    vtrans_kernel<<<BATCH * NHEAD, 256, 0, stream>>>(qkv, Vt);
    fused_attn_kernel<<<dim3(13, BATCH * NHEAD), 256, 0, stream>>>(
        qkv, qks, Vt, attn, o);

    mfma_gemm<true, true, false, false><<<dim3(512 / 128, MPAD / 128), 256, 0, stream>>>(
        o, wt_out + (size_t)l * 512 * 512, out_b + l * DMODEL, x, x, ROWS, 512, 512);

    ln_kernel<<<MPAD, 256, 0, stream>>>(x, ln2_g + l * DMODEL, ln2_b + l * DMODEL, h);

    mfma_gemm<true, false, true, true><<<dim3(2048 / 128, MPAD / 128), 256, 0, stream>>>(
        h, wt_ff1 + (size_t)l * 2048 * 512, ff_b1 + l * FCDIM, nullptr, ff1, ROWS, 512, 2048);
    mfma_gemm<true, true, false, false><<<dim3(512 / 128, MPAD / 128), 256, 0, stream>>>(
        ff1, wt_ff2 + (size_t)l * 512 * 2048, ff_b2 + l * DMODEL, x, x, ROWS, 2048, 512);
  }

  final_kernel<<<BATCH, 512, 0, stream>>>(x, gen_g, gen_bl, gen_W, gen_b, out_f);
}